// Round 4
// baseline (91560.187 us; speedup 1.0000x reference)
//
#include <hip/hip_runtime.h>
#include <math.h>

// ESN reservoir, persistent kernel, round 4.
// h_t = tanh(x_t Win^T + h_{t-1} W^T); out_t = h_t Wout^T + b
//
// Round 4 = round 3 + ONE fix: global_load_lds global address now carries the
// per-lane offset (+lane granule). Round 3 loaded one granule replicated 64x.
//
//  - 256 blocks x 512 threads (8 waves). Block owns 8 rows x 16 batches.
//    Wave w: rows blk*8 + (w>>1)*2 .. +2, batches (w&1)*8 .. +8.
//  - h kept in bf16 (recurrence quantization error ~5e-4 << 2.2e-2 threshold).
//    Full h (16x2048 bf16 = 64KB) staged to STATIC shared via global_load_lds.
//  - Cooperative launch; on ANY error fall back to plain launch (256 blocks
//    co-resident on 256 CUs; barrier spin has a bail-out -> never hangs).
//  - Grid barrier: monotonic epoch counter, agent-scope atomics + fences.
//  - Output: per-block 48 partials -> atomicAdd into 4 buckets in ws;
//    tiny finalize kernel adds buckets + bias.

#define RDIM   2048
#define BATCH  16
#define TSTEPS 2048
#define NIN    3
#define NOUT   3
#define NBLK   256
#define NTHR   512
#define NBUCKET 4

#define PART_ELEMS (TSTEPS * NBUCKET * BATCH * NOUT)  // 393216 floats
#define HB_FLOATS  ((BATCH * RDIM) / 2)               // bf16 buffer as floats
#define OFF_PART 0
#define OFF_H0   (PART_ELEMS)
#define OFF_H1   (PART_ELEMS + HB_FLOATS)
#define OFF_CTR  (PART_ELEMS + 2 * HB_FLOATS)

__device__ __forceinline__ void load_lds16(const void* g, void* l) {
    __builtin_amdgcn_global_load_lds(
        (const __attribute__((address_space(1))) void*)g,
        (__attribute__((address_space(3))) void*)l, 16, 0, 0);
}

__device__ __forceinline__ float bf16lo(unsigned u) {
    union { unsigned u; float f; } c; c.u = u << 16; return c.f;
}
__device__ __forceinline__ float bf16hi(unsigned u) {
    union { unsigned u; float f; } c; c.u = u & 0xffff0000u; return c.f;
}
__device__ __forceinline__ unsigned short f2bf(float f) {
    union { float f; unsigned u; } c; c.f = f;
    unsigned r = c.u + 0x7fffu + ((c.u >> 16) & 1u);   // round-to-nearest-even
    return (unsigned short)(r >> 16);
}

extern "C" __global__ void __launch_bounds__(NTHR, 1) esn_persist(
    const float* __restrict__ W,               // [R,R]
    const float* __restrict__ Win,             // [R,3]
    const float* __restrict__ x,               // [B,T,3]
    const float* __restrict__ Wout,            // [3,R]
    float* __restrict__ part,                  // [T][4][48]
    unsigned short* __restrict__ hb0,          // [B,R] bf16
    unsigned short* __restrict__ hb1,
    unsigned* __restrict__ ctr)
{
    __shared__ unsigned short hs[BATCH * RDIM];  // 64 KB; reused post-compute

    const int tid  = threadIdx.x;
    const int lane = tid & 63;
    const int w    = tid >> 6;                  // wave 0..7
    const int blk  = blockIdx.x;
    const int row0 = blk * 8;
    const int rbase = row0 + (w >> 1) * 2;      // 2 rows
    const int bbase = (w & 1) * 8;              // 8 batches

    const float4* W4 = (const float4*)W;

    for (int t = 0; t < TSTEPS; ++t) {
        const unsigned short* hprev = (t & 1) ? hb1 : hb0;
        unsigned short*       hnext = (t & 1) ? hb0 : hb1;

        // ---- stage full h (bf16, 64KB) -> LDS: 4096 x 16B granules ----
        // Global address is PER-LANE (slot_wave + lane); LDS dest is the
        // wave-uniform base, HW scatters lane i at base + i*16. (Round 3 bug:
        // missing +lane on the global side.)
#pragma unroll
        for (int i = 0; i < 8; ++i) {
            const int slot_wave = i * NTHR + w * 64;          // 16B-granule idx
            load_lds16(hprev + (size_t)(slot_wave + lane) * 8,
                       hs + (size_t)slot_wave * 8);
        }
        __syncthreads();

        // ---- compute acc[r][b] over lane's k-slice (8 bf16 per granule) ----
        float acc[2][8];
#pragma unroll
        for (int r = 0; r < 2; ++r)
#pragma unroll
            for (int b = 0; b < 8; ++b) acc[r][b] = 0.f;

        const uint4* h16 = (const uint4*)hs;    // 8 bf16 per uint4
#pragma unroll
        for (int c = 0; c < 4; ++c) {
            const int g = c * 64 + lane;        // granule: k = g*8 .. +8
            float4 wv[2][2];
#pragma unroll
            for (int r = 0; r < 2; ++r) {
                const float4* Wp = W4 + (size_t)(rbase + r) * (RDIM / 4) + g * 2;
                wv[r][0] = Wp[0];
                wv[r][1] = Wp[1];
            }
#pragma unroll
            for (int b = 0; b < 8; ++b) {
                uint4 q = h16[(bbase + b) * (RDIM / 8) + g];
                float f0 = bf16lo(q.x), f1 = bf16hi(q.x);
                float f2 = bf16lo(q.y), f3 = bf16hi(q.y);
                float f4 = bf16lo(q.z), f5 = bf16hi(q.z);
                float f6 = bf16lo(q.w), f7 = bf16hi(q.w);
#pragma unroll
                for (int r = 0; r < 2; ++r) {
                    acc[r][b] += wv[r][0].x * f0 + wv[r][0].y * f1
                               + wv[r][0].z * f2 + wv[r][0].w * f3
                               + wv[r][1].x * f4 + wv[r][1].y * f5
                               + wv[r][1].z * f6 + wv[r][1].w * f7;
                }
            }
        }

        // ---- fold upper 32 lanes, then 32-lane LDS transpose reduce ----
        float v[16];
#pragma unroll
        for (int i = 0; i < 16; ++i) {
            float a = acc[i >> 3][i & 7];
            v[i] = a + __shfl_xor(a, 32, 64);
        }
        __syncthreads();                         // staged h no longer needed

        float* red  = (float*)hs + w * (32 * 17);     // 544 floats per wave
        float* hblk = (float*)hs + 8192;              // [8][16] at byte 32768
        if (lane < 32) {
#pragma unroll
            for (int i = 0; i < 16; ++i)
                red[lane * 17 + ((i + lane) & 15)] = v[i];
        }
        __syncthreads();
        if (lane < 16) {
            float s = 0.f;
#pragma unroll
            for (int l = 0; l < 32; ++l)
                s += red[l * 17 + ((lane + l) & 15)];
            const int r   = lane >> 3;            // 0..1
            const int b   = lane & 7;
            const int row = rbase + r;
            const int bg  = bbase + b;
            float pre = s;
#pragma unroll
            for (int c = 0; c < NIN; ++c)
                pre += Win[row * NIN + c] * x[((size_t)bg * TSTEPS + t) * NIN + c];
            float h = tanhf(pre);
            hnext[(size_t)bg * RDIM + row] = f2bf(h);
            hblk[((w >> 1) * 2 + r) * 16 + bg] = h;   // fp32 h for projection
        }
        __syncthreads();

        // ---- out partials: 48 values, bucketed atomics ----
        if (tid < BATCH * NOUT) {
            const int b = tid / NOUT;
            const int k = tid % NOUT;
            float s = 0.f;
#pragma unroll
            for (int rr = 0; rr < 8; ++rr)
                s += Wout[k * RDIM + row0 + rr] * hblk[rr * 16 + b];
            atomicAdd(&part[((size_t)t * NBUCKET + (blk & (NBUCKET - 1))) * 48 + tid], s);
        }

        // ---- grid barrier (monotonic epoch) ----
        __threadfence();
        __syncthreads();
        if (tid == 0) {
            __hip_atomic_fetch_add(ctr, 1u, __ATOMIC_ACQ_REL, __HIP_MEMORY_SCOPE_AGENT);
            const unsigned target = (unsigned)gridDim.x * (unsigned)(t + 1);
            long spins = 0;
            while (__hip_atomic_load(ctr, __ATOMIC_ACQUIRE, __HIP_MEMORY_SCOPE_AGENT) < target) {
                __builtin_amdgcn_s_sleep(2);
                if (++spins > (1L << 22)) break;   // bail-out: never hang
            }
        }
        __syncthreads();
    }
}

extern "C" __global__ void __launch_bounds__(256) esn_out(
    const float* __restrict__ part, const float* __restrict__ bias,
    float* __restrict__ out)
{
    const int i = blockIdx.x * 256 + threadIdx.x;   // over B*T*NOUT
    if (i >= BATCH * TSTEPS * NOUT) return;
    const int k = i % NOUT;
    const int t = (i / NOUT) % TSTEPS;
    const int b = i / (NOUT * TSTEPS);
    float s = bias[k];
#pragma unroll
    for (int u = 0; u < NBUCKET; ++u)
        s += part[((size_t)t * NBUCKET + u) * 48 + b * NOUT + k];
    out[i] = s;
}

extern "C" void kernel_launch(void* const* d_in, const int* in_sizes, int n_in,
                              void* d_out, int out_size, void* d_ws, size_t ws_size,
                              hipStream_t stream) {
    const float* x    = (const float*)d_in[0];
    const float* Win  = (const float*)d_in[1];
    const float* W    = (const float*)d_in[2];
    const float* Wout = (const float*)d_in[3];
    const float* bout = (const float*)d_in[4];
    float* out = (float*)d_out;

    float* wsf = (float*)d_ws;
    float*          part = wsf + OFF_PART;
    unsigned short* hb0  = (unsigned short*)(wsf + OFF_H0);
    unsigned short* hb1  = (unsigned short*)(wsf + OFF_H1);
    unsigned*       ctr  = (unsigned*)(wsf + OFF_CTR);

    // zero part buckets + h buffers + barrier counter (~1.7 MB)
    hipMemsetAsync(d_ws, 0, (size_t)(OFF_CTR + 1) * sizeof(float), stream);

    void* args[] = {(void*)&W, (void*)&Win, (void*)&x, (void*)&Wout,
                    (void*)&part, (void*)&hb0, (void*)&hb1, (void*)&ctr};
    hipError_t e = hipLaunchCooperativeKernel((const void*)esn_persist,
                                              dim3(NBLK), dim3(NTHR),
                                              args, 0, stream);
    if (e != hipSuccess) {
        // Fallback: plain launch. 256 blocks on 256 CUs are co-resident in
        // practice; the barrier's spin bail-out guarantees no hang regardless.
        esn_persist<<<dim3(NBLK), dim3(NTHR), 0, stream>>>(
            W, Win, x, Wout, part, hb0, hb1, ctr);
    }

    esn_out<<<dim3((BATCH * TSTEPS * NOUT + 255) / 256), dim3(256), 0, stream>>>(
        part, bout, out);
}

// Round 5
// 63887.640 us; speedup vs baseline: 1.4331x; 1.4331x over previous
//
#include <hip/hip_runtime.h>
#include <math.h>

// ESN reservoir, persistent kernel, round 5.
// h_t = tanh(x_t Win^T + h_{t-1} W^T); out_t = h_t Wout^T + b
//
// Round-4 diagnosis: VALUBusy 7.4% -> 93% stalled on serialized device-scope
// atomics (12288 atomicAdds/step onto ~12 lines) + agent fences.
// Round-5 structure:
//  - NO contended atomics, NO cache-wide fences.
//  - h handoff: write-through stores (RELAXED SYSTEM atomics -> sc0 sc1) +
//    staging via global_load_lds aux=0x11 (SC0|SC1: bypass stale L2).
//    W/Win/Wout/x stay L1/L2-warm (never invalidated).
//  - out[t-1]: rotating designated block computes the FULL projection from
//    its own LDS copy of h (every block stages all of h anyway), overlapped
//    with other blocks' barrier wait. No atomics, no finalize kernel.
//  - Barrier: per-block flag store (distinct dwords) -> block 0 polls all
//    256 flags (256 threads) -> one relaxed 'go' store -> others poll go.
//    All spins bounded: worst case wrong answer, never a hang.

#define RDIM   2048
#define BATCH  16
#define TSTEPS 2048
#define NIN    3
#define NOUT   3
#define NBLK   256
#define NTHR   512

#define HB_U32     ((BATCH * RDIM) / 2)     // h buffer in dwords (2 bf16/dword)
#define OFF_H0_U32 0
#define OFF_H1_U32 (HB_U32)
#define OFF_FLAGS  (2 * HB_U32)             // 256 dwords
#define OFF_GO     (2 * HB_U32 + 256)       // 64B-aligned (byte 132096)
#define SPIN_MAX   (1L << 20)

// CPol bits (LLVM SIDefines): GLC/SC0=1, SLC/NT=2, SCC/SC1=16
#define CPOL_SC0_SC1 0x11

__device__ __forceinline__ void load_lds16_coherent(const void* g, void* l) {
    __builtin_amdgcn_global_load_lds(
        (const __attribute__((address_space(1))) void*)g,
        (__attribute__((address_space(3))) void*)l, 16, 0, CPOL_SC0_SC1);
}

__device__ __forceinline__ float bf16lo(unsigned u) {
    union { unsigned u; float f; } c; c.u = u << 16; return c.f;
}
__device__ __forceinline__ float bf16hi(unsigned u) {
    union { unsigned u; float f; } c; c.u = u & 0xffff0000u; return c.f;
}
__device__ __forceinline__ unsigned f2bf(float f) {
    union { float f; unsigned u; } c; c.f = f;
    unsigned r = c.u + 0x7fffu + ((c.u >> 16) & 1u);   // round-to-nearest-even
    return r >> 16;
}

extern "C" __global__ void __launch_bounds__(NTHR, 1) esn_persist(
    const float* __restrict__ W,       // [R,R]
    const float* __restrict__ Win,     // [R,3]
    const float* __restrict__ x,       // [B,T,3]
    const float* __restrict__ Wout,    // [3,R]
    const float* __restrict__ bout,    // [3]
    unsigned* hb0,                     // [B*R/2] packed bf16x2
    unsigned* hb1,
    unsigned* flags,                   // [256]
    unsigned* go,
    float* __restrict__ out)           // [B,T,3]
{
    __shared__ unsigned short hs[BATCH * RDIM];  // 64 KB, intact all step
    __shared__ float red[8][544];                // 17.4 KB reduce scratch
    __shared__ float hblk[8][16];                // block's 8 rows of h_new

    const int tid  = threadIdx.x;
    const int lane = tid & 63;
    const int w    = tid >> 6;                  // wave 0..7
    const int blk  = blockIdx.x;
    const int row0 = blk * 8;
    const int rbase = row0 + (w >> 1) * 2;      // 2 rows per wave
    const int bbase = (w & 1) * 8;              // 8 batches per wave

    const float4* W4 = (const float4*)W;

    for (int t = 0; t <= TSTEPS; ++t) {
        const unsigned* hprev = (t & 1) ? hb1 : hb0;
        unsigned*       hnext = (t & 1) ? hb0 : hb1;

        // ---- stage full h (64KB) -> LDS; L2-bypassing (sc0 sc1) ----
#pragma unroll
        for (int i = 0; i < 8; ++i) {
            const int base = i * 512 + w * 64;              // 16B granule idx
            load_lds16_coherent(hprev + (size_t)(base + lane) * 4,
                                hs + (size_t)base * 8);
        }
        __syncthreads();   // (#1) staging complete

        if (t < TSTEPS) {
            // ---- recurrence: acc[r][b] over lane's k-slice ----
            float acc[2][8];
#pragma unroll
            for (int r = 0; r < 2; ++r)
#pragma unroll
                for (int b = 0; b < 8; ++b) acc[r][b] = 0.f;

            const uint4* h16 = (const uint4*)hs;    // 8 bf16 per uint4
#pragma unroll
            for (int c = 0; c < 4; ++c) {
                const int g = c * 64 + lane;        // k = g*8 .. +8
                float4 wv[2][2];
#pragma unroll
                for (int r = 0; r < 2; ++r) {
                    const float4* Wp = W4 + (size_t)(rbase + r) * (RDIM / 4) + g * 2;
                    wv[r][0] = Wp[0];
                    wv[r][1] = Wp[1];
                }
#pragma unroll
                for (int b = 0; b < 8; ++b) {
                    uint4 q = h16[(bbase + b) * (RDIM / 8) + g];
                    float f0 = bf16lo(q.x), f1 = bf16hi(q.x);
                    float f2 = bf16lo(q.y), f3 = bf16hi(q.y);
                    float f4 = bf16lo(q.z), f5 = bf16hi(q.z);
                    float f6 = bf16lo(q.w), f7 = bf16hi(q.w);
#pragma unroll
                    for (int r = 0; r < 2; ++r) {
                        acc[r][b] += wv[r][0].x * f0 + wv[r][0].y * f1
                                   + wv[r][0].z * f2 + wv[r][0].w * f3
                                   + wv[r][1].x * f4 + wv[r][1].y * f5
                                   + wv[r][1].z * f6 + wv[r][1].w * f7;
                    }
                }
            }

            // ---- reduce 64 lanes -> 16 (r,b) sums per wave ----
            float v[16];
#pragma unroll
            for (int i = 0; i < 16; ++i) {
                float a = acc[i >> 3][i & 7];
                v[i] = a + __shfl_xor(a, 32, 64);
            }
            if (lane < 32) {
#pragma unroll
                for (int i = 0; i < 16; ++i)
                    red[w][lane * 17 + ((i + lane) & 15)] = v[i];
            }
            __syncthreads();   // (#2a) red ready (also: everyone done with v)
            if (lane < 16) {
                float s = 0.f;
#pragma unroll
                for (int l = 0; l < 32; ++l)
                    s += red[w][l * 17 + ((lane + l) & 15)];
                const int r   = lane >> 3;
                const int b   = lane & 7;
                const int row = rbase + r;
                const int bg  = bbase + b;
                float pre = s;
#pragma unroll
                for (int c = 0; c < NIN; ++c)
                    pre += Win[row * NIN + c] * x[((size_t)bg * TSTEPS + t) * NIN + c];
                hblk[(w >> 1) * 2 + r][bg] = tanhf(pre);
            }
            __syncthreads();   // (#2b) hblk complete

            // ---- write-through h_new strips: wave 0, 64 packed dwords ----
            if (w == 0) {
                const int bg = lane >> 2;          // batch 0..15
                const int d  = lane & 3;           // dword within 8-row strip
                unsigned lo = f2bf(hblk[2 * d][bg]);
                unsigned hi = f2bf(hblk[2 * d + 1][bg]);
                __hip_atomic_store(&hnext[bg * (RDIM / 2) + blk * 4 + d],
                                   lo | (hi << 16),
                                   __ATOMIC_RELAXED, __HIP_MEMORY_SCOPE_SYSTEM);
                __builtin_amdgcn_s_waitcnt(0);     // drain before flagging
            }
            __syncthreads();   // (#2c) all h stores globally visible

            if (tid == 0)
                __hip_atomic_store(&flags[blk], (unsigned)(t + 1),
                                   __ATOMIC_RELAXED, __HIP_MEMORY_SCOPE_SYSTEM);
        }

        // ---- projection of h_{t-1} (in hs) by the designated block ----
        // Placed after flag-arrival: overlaps other blocks' barrier wait.
        if (t > 0 && blk == ((t - 1) & (NBLK - 1))) {
            const int o = t - 1;
#pragma unroll
            for (int p = w * 6; p < w * 6 + 6; ++p) {
                const int b = p / NOUT;
                const int k = p % NOUT;
                float a = 0.f;
#pragma unroll
                for (int j = 0; j < 32; ++j) {
                    const int r = j * 64 + lane;
                    a += bf16lo(hs[b * RDIM + r]) * Wout[k * RDIM + r];
                }
#pragma unroll
                for (int off = 32; off >= 1; off >>= 1)
                    a += __shfl_xor(a, off, 64);
                if (lane == 0)
                    out[((size_t)b * TSTEPS + o) * NOUT + k] = a + bout[k];
            }
        }

        // ---- barrier: flags -> block0 -> go ----
        if (t < TSTEPS) {
            if (blk == 0) {
                if (tid < NBLK) {
                    long spins = 0;
                    while (__hip_atomic_load(&flags[tid], __ATOMIC_RELAXED,
                                             __HIP_MEMORY_SCOPE_SYSTEM) < (unsigned)(t + 1)) {
                        __builtin_amdgcn_s_sleep(2);
                        if (++spins > SPIN_MAX) break;   // never hang
                    }
                }
                __syncthreads();   // (#3)
                if (tid == 0)
                    __hip_atomic_store(go, (unsigned)(t + 1),
                                       __ATOMIC_RELAXED, __HIP_MEMORY_SCOPE_SYSTEM);
            } else {
                if (tid == 0) {
                    long spins = 0;
                    while (__hip_atomic_load(go, __ATOMIC_RELAXED,
                                             __HIP_MEMORY_SCOPE_SYSTEM) < (unsigned)(t + 1)) {
                        __builtin_amdgcn_s_sleep(2);
                        if (++spins > SPIN_MAX) break;   // never hang
                    }
                }
                __syncthreads();   // (#3)
            }
        }
    }
}

extern "C" void kernel_launch(void* const* d_in, const int* in_sizes, int n_in,
                              void* d_out, int out_size, void* d_ws, size_t ws_size,
                              hipStream_t stream) {
    const float* x    = (const float*)d_in[0];
    const float* Win  = (const float*)d_in[1];
    const float* W    = (const float*)d_in[2];
    const float* Wout = (const float*)d_in[3];
    const float* bout = (const float*)d_in[4];
    float* out = (float*)d_out;

    unsigned* wsu  = (unsigned*)d_ws;
    unsigned* hb0   = wsu + OFF_H0_U32;
    unsigned* hb1   = wsu + OFF_H1_U32;
    unsigned* flags = wsu + OFF_FLAGS;
    unsigned* go    = wsu + OFF_GO;

    // zero h0 (+h1 for tidiness) + flags + go  (~132 KB)
    hipMemsetAsync(d_ws, 0, (size_t)(OFF_GO + 16) * sizeof(unsigned), stream);

    void* args[] = {(void*)&W, (void*)&Win, (void*)&x, (void*)&Wout, (void*)&bout,
                    (void*)&hb0, (void*)&hb1, (void*)&flags, (void*)&go, (void*)&out};
    hipError_t e = hipLaunchCooperativeKernel((const void*)esn_persist,
                                              dim3(NBLK), dim3(NTHR),
                                              args, 0, stream);
    if (e != hipSuccess) {
        // Fallback: plain launch. 256 blocks co-resident on 256 CUs; bounded
        // spins guarantee no hang regardless.
        esn_persist<<<dim3(NBLK), dim3(NTHR), 0, stream>>>(
            W, Win, x, Wout, bout, hb0, hb1, flags, go, out);
    }
}